// Round 8
// baseline (56.738 us; speedup 1.0000x reference)
//
#include <hip/hip_runtime.h>

#define BATCH   2048
#define IN_DIM  16384
#define OUT_DIM 16384
#define NGATES  16
#define ROWS_PER_BLOCK 2
#define NBLK (BATCH / ROWS_PER_BLOCK)   // 1024 blocks

typedef float    f32x4 __attribute__((ext_vector_type(4)));
typedef _Float16 f16x4 __attribute__((ext_vector_type(4)));
typedef _Float16 f16x8 __attribute__((ext_vector_type(8)));

// COEFF[16][4] from the reference, hard-coded.
__constant__ float c_coeff[NGATES][4] = {
    {0, 0, 0, 0},  {0, 0, 0, 1},  {0, 1, 0, -1}, {0, 1, 0, 0},
    {0, 0, 1, -1}, {0, 0, 1, 0},  {0, 1, 1, -2}, {0, 1, 1, -1},
    {1, -1, -1, 1},{1, -1, -1, 2},{1, 0, -1, 0}, {1, 0, -1, 1},
    {1, -1, 0, 0}, {1, -1, 0, 1}, {1, 0, 0, -1}, {1, 0, 0, 0}
};

// Kernel 1: per output column j, fold softmax(weights[j,:]) @ COEFF into
// W[j] stored as f16x4 (8 B), and pack gather indices into one uint32.
__global__ __launch_bounds__(256) void prep_kernel(
    const float* __restrict__ weights,
    const int*   __restrict__ idx_a,
    const int*   __restrict__ idx_b,
    f16x4*       __restrict__ Wh,
    unsigned*    __restrict__ Ipk)
{
    int j = blockIdx.x * blockDim.x + threadIdx.x;
    if (j >= OUT_DIM) return;

    const float4* wrow = reinterpret_cast<const float4*>(weights + (size_t)j * NGATES);
    float v[NGATES];
    float4 q0 = wrow[0], q1 = wrow[1], q2 = wrow[2], q3 = wrow[3];
    v[0]=q0.x; v[1]=q0.y; v[2]=q0.z; v[3]=q0.w;
    v[4]=q1.x; v[5]=q1.y; v[6]=q1.z; v[7]=q1.w;
    v[8]=q2.x; v[9]=q2.y; v[10]=q2.z; v[11]=q2.w;
    v[12]=q3.x; v[13]=q3.y; v[14]=q3.z; v[15]=q3.w;

    float m = v[0];
#pragma unroll
    for (int g = 1; g < NGATES; ++g) m = fmaxf(m, v[g]);
    float s = 0.f;
#pragma unroll
    for (int g = 0; g < NGATES; ++g) { v[g] = expf(v[g] - m); s += v[g]; }
    float inv = 1.0f / s;

    float c0 = 0.f, c1 = 0.f, c2 = 0.f, c3 = 0.f;
#pragma unroll
    for (int g = 0; g < NGATES; ++g) {
        c0 += v[g] * c_coeff[g][0];
        c1 += v[g] * c_coeff[g][1];
        c2 += v[g] * c_coeff[g][2];
        c3 += v[g] * c_coeff[g][3];
    }
    f16x4 h;
    h.x = (_Float16)(c0 * inv); h.y = (_Float16)(c1 * inv);
    h.z = (_Float16)(c2 * inv); h.w = (_Float16)(c3 * inv);
    Wh[j] = h;
    Ipk[j] = (unsigned)idx_a[j] | ((unsigned)idx_b[j] << 16);   // both < 16384
}

// Compute one row's 16 KB of outputs (8 groups of 4 per thread) with a
// depth-1 idx/W prefetch pipeline. rowh = f16-staged x row in LDS.
__device__ __forceinline__ void compute_row(
    const _Float16* __restrict__ rowh,
    const f16x8* __restrict__ Wh8,
    const uint4* __restrict__ Ipk4,
    float* __restrict__ orow, int tid)
{
    uint4 qc = Ipk4[tid];
    f16x8 wa = Wh8[(size_t)tid * 2];
    f16x8 wb = Wh8[(size_t)tid * 2 + 1];
    f32x4* o4 = reinterpret_cast<f32x4*>(orow);

#pragma unroll
    for (int k = 0; k < OUT_DIM / 4 / 512; ++k) {     // 8 groups
        uint4 qn;  f16x8 wan, wbn;
        if (k + 1 < OUT_DIM / 4 / 512) {
            const int j4n = tid + (k + 1) * 512;
            qn  = Ipk4[j4n];
            wan = Wh8[(size_t)j4n * 2];
            wbn = Wh8[(size_t)j4n * 2 + 1];
        }

        float a0 = (float)rowh[qc.x & 0xFFFFu], b0 = (float)rowh[qc.x >> 16];
        float a1 = (float)rowh[qc.y & 0xFFFFu], b1 = (float)rowh[qc.y >> 16];
        float a2 = (float)rowh[qc.z & 0xFFFFu], b2 = (float)rowh[qc.z >> 16];
        float a3 = (float)rowh[qc.w & 0xFFFFu], b3 = (float)rowh[qc.w >> 16];

        f32x4 res;
        res.x = (float)wa[0] + (float)wa[1] * a0 + (float)wa[2] * b0 + (float)wa[3] * (a0 * b0);
        res.y = (float)wa[4] + (float)wa[5] * a1 + (float)wa[6] * b1 + (float)wa[7] * (a1 * b1);
        res.z = (float)wb[0] + (float)wb[1] * a2 + (float)wb[2] * b2 + (float)wb[3] * (a2 * b2);
        res.w = (float)wb[4] + (float)wb[5] * a3 + (float)wb[6] * b3 + (float)wb[7] * (a3 * b3);
        __builtin_nontemporal_store(res, &o4[tid + k * 512]);

        qc = qn; wa = wan; wb = wbn;
    }
}

// Kernel 2: 1024 blocks x 512 threads, 2 rows/block, single 32 KB f16 LDS
// buffer (4 blocks/CU). Row 1's 8 f32x4 global loads are issued into
// REGISTERS immediately after row 0's stage barrier — they retire from HBM
// under row 0's entire compute phase (no LDS hazard: the buffer is only
// rewritten after the post-compute barrier). Halves the per-row serial
// stage cost and block churn vs 1 row/block.
__global__ __launch_bounds__(512, 8) void logic_row_kernel(
    const float* __restrict__ x,
    const f16x8* __restrict__ Wh8,
    const uint4* __restrict__ Ipk4,
    float*       __restrict__ out)
{
    __shared__ _Float16 rowh[IN_DIM];   // 32 KB
    const int tid = threadIdx.x;
    const int r0  = blockIdx.x * ROWS_PER_BLOCK;

    f16x4* rhw = reinterpret_cast<f16x4*>(rowh);
    f32x4  s[8];

    // --- Stage row 0: coalesced loads -> f16 -> LDS ---
    {
        const f32x4* xr = reinterpret_cast<const f32x4*>(x + (size_t)r0 * IN_DIM);
#pragma unroll
        for (int k = 0; k < 8; ++k) s[k] = xr[tid + k * 512];
#pragma unroll
        for (int k = 0; k < 8; ++k) {
            f16x4 h;
            h.x = (_Float16)s[k].x; h.y = (_Float16)s[k].y;
            h.z = (_Float16)s[k].z; h.w = (_Float16)s[k].w;
            rhw[tid + k * 512] = h;
        }
    }
    __syncthreads();

    // --- Issue row 1's global loads now; retire under row 0's compute ---
    {
        const f32x4* xr = reinterpret_cast<const f32x4*>(x + (size_t)(r0 + 1) * IN_DIM);
#pragma unroll
        for (int k = 0; k < 8; ++k) s[k] = xr[tid + k * 512];
    }

    compute_row(rowh, Wh8, Ipk4, out + (size_t)r0 * OUT_DIM, tid);

    __syncthreads();   // all LDS reads of row 0 done

    // --- Write row 1 to LDS (loads already in flight/retired) ---
#pragma unroll
    for (int k = 0; k < 8; ++k) {
        f16x4 h;
        h.x = (_Float16)s[k].x; h.y = (_Float16)s[k].y;
        h.z = (_Float16)s[k].z; h.w = (_Float16)s[k].w;
        rhw[tid + k * 512] = h;
    }
    __syncthreads();

    compute_row(rowh, Wh8, Ipk4, out + (size_t)(r0 + 1) * OUT_DIM, tid);
}

extern "C" void kernel_launch(void* const* d_in, const int* in_sizes, int n_in,
                              void* d_out, int out_size, void* d_ws, size_t ws_size,
                              hipStream_t stream) {
    const float* x       = (const float*)d_in[0];
    const float* weights = (const float*)d_in[1];
    const int*   idx_a   = (const int*)d_in[2];
    const int*   idx_b   = (const int*)d_in[3];
    float* out = (float*)d_out;

    // Workspace layout: Wh (OUT_DIM f16x4 = 128 KB), Ipk (OUT_DIM uint = 64 KB)
    f16x4*    Wh  = (f16x4*)d_ws;
    unsigned* Ipk = (unsigned*)((char*)d_ws + (size_t)OUT_DIM * sizeof(f16x4));

    prep_kernel<<<(OUT_DIM + 255) / 256, 256, 0, stream>>>(weights, idx_a, idx_b, Wh, Ipk);
    logic_row_kernel<<<NBLK, 512, 0, stream>>>(x, (const f16x8*)Wh, (const uint4*)Ipk, out);
}